// Round 5
// baseline (80.175 us; speedup 1.0000x reference)
//
#include <hip/hip_runtime.h>
#include <hip/hip_fp16.h>
#include <stdint.h>

// ---------------- problem constants ----------------
#define T_DIM   16384       // S*B tokens
#define NKS     67          // K-steps of 64 ; K total = 67*64 = 4288
#define LN_EPS  1e-5f

typedef _Float16 f16;
typedef __attribute__((ext_vector_type(2))) _Float16 h2v;
typedef __attribute__((ext_vector_type(4))) _Float16 h4v;
typedef __attribute__((ext_vector_type(8))) _Float16 h8v;
typedef __attribute__((ext_vector_type(4))) float    f32x4;

union H2U { uint32_t u; h2v h; };
union H8U { uint32_t u[4]; h8v v; };

// ============================================================
// Kernel 1: pack W3-like operand into per-wave FRAGMENT order:
//   w3p[(ostrip*67 + ks)*2048 + i2*1024 + n*512 + lane*8 + j]
// value = B[o = ostrip*32+n*16+(lane&15)][k = (2ks+i2)*32 + (lane>>4)*8 + j]
// slices (2ks+i2): 0..127 wW3 ; 128..131 wb3 (A=x) ; 132 bW3 (A=h2b) ; 133 zeros.
// GEMM reads each fragment as ONE contiguous 1KB wave-burst.
// ============================================================
__global__ __launch_bounds__(256) void prep_w3(
    const float* __restrict__ wW3, const float* __restrict__ wb3,
    const float* __restrict__ bW3, f16* __restrict__ w3p)
{
  const int idx  = blockIdx.x * 256 + threadIdx.x;   // 0..68607
  const int lane = idx & 63;
  int rest = idx >> 6;
  const int n  = rest & 1;  rest >>= 1;
  const int i2 = rest & 1;  rest >>= 1;              // rest in [0,268)
  const int ks = rest % 67;
  const int os = rest / 67;
  if (os >= 4) return;

  const int o     = os * 32 + n * 16 + (lane & 15);
  const int slice = ks * 2 + i2;
  const int h0    = (lane >> 4) * 8;

  float v[8];
  if (slice < 133) {
    const float* src;
    if      (slice < 128) src = wW3 + ((size_t)o * 128 + slice) * 32 + h0;
    else if (slice < 132) src = wb3 + (size_t)o * 128 + (slice - 128) * 32 + h0;
    else                  src = bW3 + (size_t)o * 32 + h0;
    float4 a = *(const float4*)src;
    float4 b = *(const float4*)(src + 4);
    v[0]=a.x; v[1]=a.y; v[2]=a.z; v[3]=a.w; v[4]=b.x; v[5]=b.y; v[6]=b.z; v[7]=b.w;
  } else {
#pragma unroll
    for (int j = 0; j < 8; ++j) v[j] = 0.f;
  }
  h8v pk;
#pragma unroll
  for (int j = 0; j < 8; ++j) pk[j] = (f16)v[j];
  *(h8v*)(w3p + ((size_t)(os * 67 + ks) * 2048 + i2 * 1024 + n * 512 + lane * 8)) = pk;
}

// ============================================================
// Kernel 2: hyper-MLP (thread-per-token, branch-uniform blocks) + x->f16 cast.
// blocks 0..63: weight branch ; 64..127: bias branch. 256 thr/block.
// Also converts a 16384-float strip of x to f16 (coalesced).
// ============================================================
__global__ __launch_bounds__(256) void hyper_kernel(
    const float* __restrict__ x, const float* __restrict__ z,
    const float* __restrict__ wW1, const float* __restrict__ wb1,
    const float* __restrict__ wg1, const float* __restrict__ wbe1,
    const float* __restrict__ wW2, const float* __restrict__ wb2,
    const float* __restrict__ wg2, const float* __restrict__ wbe2,
    const float* __restrict__ bW1, const float* __restrict__ bb1,
    const float* __restrict__ bg1, const float* __restrict__ bbe1,
    const float* __restrict__ bW2, const float* __restrict__ bb2,
    const float* __restrict__ bg2, const float* __restrict__ bbe2,
    f16* __restrict__ xf, f16* __restrict__ h2w, f16* __restrict__ h2b)
{
  const int tid = threadIdx.x;
  const int bid = blockIdx.x;

  // ---- x -> f16, block-strided, coalesced ----
  {
    const size_t base = (size_t)bid * 16384;
#pragma unroll
    for (int u = 0; u < 16; ++u) {
      const size_t off = base + u * 1024 + tid * 4;
      float4 a = *(const float4*)(x + off);
      h4v p; p[0] = (f16)a.x; p[1] = (f16)a.y; p[2] = (f16)a.z; p[3] = (f16)a.w;
      *(h4v*)(xf + off) = p;
    }
  }

  // ---- hyper MLP, one token-eval per thread ----
  const int br  = bid >> 6;                    // 0 = weight, 1 = bias branch
  const int tok = (bid & 63) * 256 + tid;
  const float* W1  = br ? bW1  : wW1;  const float* b1  = br ? bb1  : wb1;
  const float* g1  = br ? bg1  : wg1;  const float* be1 = br ? bbe1 : wbe1;
  const float* W2  = br ? bW2  : wW2;  const float* b2  = br ? bb2  : wb2;
  const float* g2  = br ? bg2  : wg2;  const float* be2 = br ? bbe2 : wbe2;
  f16* dst = (br ? h2b : h2w) + (size_t)tok * 32;

  const float z0 = z[tok * 3 + 0], z1 = z[tok * 3 + 1], z2 = z[tok * 3 + 2];

  float h1[32];
  float s = 0.f, s2 = 0.f;
#pragma unroll
  for (int j = 0; j < 32; ++j) {
    float v = W1[j * 3] * z0 + W1[j * 3 + 1] * z1 + W1[j * 3 + 2] * z2 + b1[j];
    h1[j] = v; s += v; s2 += v * v;
  }
  float mu  = s * (1.f / 32.f);
  float var = fmaxf(s2 * (1.f / 32.f) - mu * mu, 0.f);
  float rr  = rsqrtf(var + LN_EPS);
#pragma unroll
  for (int j = 0; j < 32; ++j)
    h1[j] = fmaxf((h1[j] - mu) * rr * g1[j] + be1[j], 0.f);

  float h2a[32];
  s = 0.f; s2 = 0.f;
#pragma unroll
  for (int j = 0; j < 32; ++j) {
    float acc = b2[j];
#pragma unroll
    for (int kk = 0; kk < 8; ++kk) {
      float4 w = *(const float4*)&W2[j * 32 + kk * 4];
      acc += w.x * h1[kk * 4] + w.y * h1[kk * 4 + 1]
           + w.z * h1[kk * 4 + 2] + w.w * h1[kk * 4 + 3];
    }
    h2a[j] = acc; s += acc; s2 += acc * acc;
  }
  mu  = s * (1.f / 32.f);
  var = fmaxf(s2 * (1.f / 32.f) - mu * mu, 0.f);
  rr  = rsqrtf(var + LN_EPS);
#pragma unroll
  for (int j8 = 0; j8 < 4; ++j8) {
    h8v pk;
#pragma unroll
    for (int j = 0; j < 8; ++j)
      pk[j] = (f16)fmaxf((h2a[j8*8+j] - mu) * rr * g2[j8*8+j] + be2[j8*8+j], 0.f);
    *(h8v*)(dst + j8 * 8) = pk;
  }
}

// ============================================================
// Kernel 3: U-GEMM, contiguous-B, barrier-free, splitK-4.
// grid 1024 = 256 token-tiles x 4 K-quarters ; 4 waves/block, wave = o-strip.
// Wave tile 64tok x 32o, 16 MFMA/iter, depth-2 reg double-buffer.
// Quarters: ks 0..16 / 17..33 / 34..50 / 51..66. Output fp32 atomicAdd
// (4 contributions; out pre-zeroed by memset). Quarter 0 adds bb3.
// ============================================================
__global__ __launch_bounds__(256, 4) void gemm_kernel(
    const f16* __restrict__ xf, const f16* __restrict__ w3p,
    const f16* __restrict__ h2w, const f16* __restrict__ h2b,
    const float* __restrict__ bb3, float* __restrict__ out)
{
  __shared__ __align__(16) f16 xs[64][136];    // x tile f16 (17.4 KB)

  const int tid  = threadIdx.x;
  const int lane = tid & 63;
  const int wid  = tid >> 6;
  const int lm   = lane & 15, hc = lane >> 4, hbase = hc * 8;
  const int tile = blockIdx.x >> 2;
  const int q    = blockIdx.x & 3;
  const int t0   = tile * 64;
  const int o0   = wid * 32;
  const int ks0   = q * 17;
  const int n_it  = (q == 3) ? 16 : 17;

  // ---- stage x tile (f16 global -> LDS), coalesced ----
  {
    const int r = tid >> 2, qq = tid & 3;
    const f16* src = xf + (size_t)(t0 + r) * 128 + qq * 32;
#pragma unroll
    for (int u = 0; u < 4; ++u)
      *(h8v*)&xs[r][qq * 32 + u * 8] = *(const h8v*)(src + u * 8);
  }

  // ---- per-lane h2 fragments (global, once) ----
  uint32_t h2p[4][4];
  short8_unused: ;
  h8v h2bf[4];
#pragma unroll
  for (int m = 0; m < 4; ++m) {
    H8U c; c.v = *(const h8v*)(h2w + (size_t)(t0 + m * 16 + lm) * 32 + hbase);
#pragma unroll
    for (int qq = 0; qq < 4; ++qq) h2p[m][qq] = c.u[qq];
  }
  if (q == 3) {
#pragma unroll
    for (int m = 0; m < 4; ++m)
      h2bf[m] = *(const h8v*)(h2b + (size_t)(t0 + m * 16 + lm) * 32 + hbase);
  }

  float bbv[2];
#pragma unroll
  for (int n = 0; n < 2; ++n)
    bbv[n] = (q == 0) ? bb3[o0 + n * 16 + lm] : 0.f;

  __syncthreads();   // xs ready; only barrier in the kernel

  // ---- contiguous B pointer: 4KB per iter, one wave-burst per fragment ----
  const f16* bp = w3p + (size_t)(wid * 67 + ks0) * 2048 + lane * 8;

#define LOADSET(S) do { \
    S[0][0] = *(const h8v*)(bp); \
    S[0][1] = *(const h8v*)(bp + 512); \
    S[1][0] = *(const h8v*)(bp + 1024); \
    S[1][1] = *(const h8v*)(bp + 1536); \
    bp += 2048; } while (0)

  f32x4 acc[4][2];
#pragma unroll
  for (int m = 0; m < 4; ++m)
#pragma unroll
    for (int n = 0; n < 2; ++n) acc[m][n] = (f32x4){0.f, 0.f, 0.f, 0.f};

  auto STEP = [&](h8v (&bs)[2][2], int ks) {
    const int ksg = ks0 + ks;
    h8v af0[4], af1[4];
    if (__builtin_expect(ksg < 64, 1)) {
#pragma unroll
      for (int m = 0; m < 4; ++m) {
        const uint32_t xp = *(const uint32_t*)&xs[m * 16 + lm][2 * ksg];
        H2U x0, x1;
        x0.u = (xp & 0xffffu) | (xp << 16);
        x1.u = (xp >> 16) | (xp & 0xffff0000u);
        H8U r0, r1;
#pragma unroll
        for (int qq = 0; qq < 4; ++qq) {
          H2U hq; hq.u = h2p[m][qq];
          H2U p0; p0.h = x0.h * hq.h; r0.u[qq] = p0.u;
          H2U p1; p1.h = x1.h * hq.h; r1.u[qq] = p1.u;
        }
        af0[m] = r0.v; af1[m] = r1.v;
      }
    } else if (ksg < 66) {
      const int s = (ksg - 64) * 2;
#pragma unroll
      for (int m = 0; m < 4; ++m) {
        af0[m] = *(const h8v*)&xs[m * 16 + lm][s * 32 + hbase];
        af1[m] = *(const h8v*)&xs[m * 16 + lm][(s + 1) * 32 + hbase];
      }
    } else {
#pragma unroll
      for (int m = 0; m < 4; ++m) { af0[m] = h2bf[m]; af1[m] = h2bf[m]; }
    }
#pragma unroll
    for (int n = 0; n < 2; ++n)
#pragma unroll
      for (int m = 0; m < 4; ++m)
        acc[m][n] = __builtin_amdgcn_mfma_f32_16x16x32_f16(af0[m], bs[0][n], acc[m][n], 0, 0, 0);
#pragma unroll
    for (int n = 0; n < 2; ++n)
#pragma unroll
      for (int m = 0; m < 4; ++m)
        acc[m][n] = __builtin_amdgcn_mfma_f32_16x16x32_f16(af1[m], bs[1][n], acc[m][n], 0, 0, 0);
  };

  h8v bA[2][2], bB[2][2];
  LOADSET(bA);            // ks = 0
  LOADSET(bB);            // ks = 1

  int ks = 0;
#pragma unroll 1
  while (ks + 2 <= n_it) {
    STEP(bA, ks);
    if (ks + 2 < n_it) LOADSET(bA);
    STEP(bB, ks + 1);
    if (ks + 3 < n_it) LOADSET(bB);
    ks += 2;
  }
  if (ks < n_it) STEP(bA, ks);

  // ---- epilogue: C/D layout col=lane&15, row=(lane>>4)*4+reg; atomic sum ----
#pragma unroll
  for (int m = 0; m < 4; ++m) {
#pragma unroll
    for (int n = 0; n < 2; ++n) {
      const int gc = o0 + n * 16 + lm;
#pragma unroll
      for (int r_ = 0; r_ < 4; ++r_) {
        const int row = t0 + m * 16 + hc * 4 + r_;
        atomicAdd(&out[(size_t)row * 128 + gc], acc[m][n][r_] + bbv[n]);
      }
    }
  }
#undef LOADSET
}

// ============================================================
extern "C" void kernel_launch(void* const* d_in, const int* in_sizes, int n_in,
                              void* d_out, int out_size, void* d_ws, size_t ws_size,
                              hipStream_t stream)
{
  const float* x    = (const float*)d_in[0];
  const float* z    = (const float*)d_in[1];
  const float* wW1  = (const float*)d_in[2];
  const float* wb1  = (const float*)d_in[3];
  const float* wg1  = (const float*)d_in[4];
  const float* wbe1 = (const float*)d_in[5];
  const float* wW2  = (const float*)d_in[6];
  const float* wb2  = (const float*)d_in[7];
  const float* wg2  = (const float*)d_in[8];
  const float* wbe2 = (const float*)d_in[9];
  const float* wW3  = (const float*)d_in[10];
  const float* wb3  = (const float*)d_in[11];
  const float* bW1  = (const float*)d_in[12];
  const float* bb1  = (const float*)d_in[13];
  const float* bg1  = (const float*)d_in[14];
  const float* bbe1 = (const float*)d_in[15];
  const float* bW2  = (const float*)d_in[16];
  const float* bb2  = (const float*)d_in[17];
  const float* bg2  = (const float*)d_in[18];
  const float* bbe2 = (const float*)d_in[19];
  const float* bW3  = (const float*)d_in[20];
  const float* bb3  = (const float*)d_in[21];

  uint8_t* ws = (uint8_t*)d_ws;
  f16* w3p = (f16*)ws;                         // 1,097,728 B
  f16* xf  = (f16*)(ws + 1097728);             // 4,194,304 B
  f16* h2w = (f16*)(ws + 1097728 + 4194304);   // 1,048,576 B
  f16* h2b = (f16*)(ws + 1097728 + 4194304 + 1048576);
  float* outf = (float*)d_out;

  hipMemsetAsync(d_out, 0, (size_t)T_DIM * 128 * sizeof(float), stream);
  hipLaunchKernelGGL(prep_w3, dim3(268), dim3(256), 0, stream, wW3, wb3, bW3, w3p);
  hipLaunchKernelGGL(hyper_kernel, dim3(128), dim3(256), 0, stream,
                     x, z,
                     wW1, wb1, wg1, wbe1, wW2, wb2, wg2, wbe2,
                     bW1, bb1, bg1, bbe1, bW2, bb2, bg2, bbe2,
                     xf, h2w, h2b);
  hipLaunchKernelGGL(gemm_kernel, dim3(1024), dim3(256), 0, stream,
                     xf, w3p, h2w, h2b, bb3, outf);
}

// Round 6
// 54.426 us; speedup vs baseline: 1.4731x; 1.4731x over previous
//
#include <hip/hip_runtime.h>
#include <hip/hip_fp16.h>
#include <stdint.h>

// ---------------- problem constants ----------------
#define T_DIM   16384       // S*B tokens
#define NKS     67          // K-steps of 64 ; K total = 67*64 = 4288
#define LN_EPS  1e-5f

typedef _Float16 f16;
typedef __attribute__((ext_vector_type(2))) _Float16 h2v;
typedef __attribute__((ext_vector_type(4))) _Float16 h4v;
typedef __attribute__((ext_vector_type(8))) _Float16 h8v;
typedef __attribute__((ext_vector_type(4))) float    f32x4;

union H2U { uint32_t u; h2v h; };
union H8U { uint32_t u[4]; h8v v; };

// ============================================================
// Kernel 1 (merged): blocks 0..267 pack W3 into per-wave fragment order;
// blocks 268..395 run the hyper-MLP (thread-per-token) + x->f16 cast.
//
// w3p[(os*67 + ks)*2048 + i2*1024 + n*512 + lane*8 + j]
//   = B[o = os*32+n*16+(lane&15)][k = (2ks+i2)*32 + (lane>>4)*8 + j]
// slices (2ks+i2): 0..127 wW3 ; 128..131 wb3 (A=x) ; 132 bW3 (A=h2b) ; 133 zeros.
// ============================================================
__global__ __launch_bounds__(256) void prep_hyper(
    const float* __restrict__ x, const float* __restrict__ z,
    const float* __restrict__ wW1, const float* __restrict__ wb1,
    const float* __restrict__ wg1, const float* __restrict__ wbe1,
    const float* __restrict__ wW2, const float* __restrict__ wb2,
    const float* __restrict__ wg2, const float* __restrict__ wbe2,
    const float* __restrict__ bW1, const float* __restrict__ bb1,
    const float* __restrict__ bg1, const float* __restrict__ bbe1,
    const float* __restrict__ bW2, const float* __restrict__ bb2,
    const float* __restrict__ bg2, const float* __restrict__ bbe2,
    const float* __restrict__ wW3, const float* __restrict__ wb3,
    const float* __restrict__ bW3,
    f16* __restrict__ w3p, f16* __restrict__ xf,
    f16* __restrict__ h2w, f16* __restrict__ h2b)
{
  const int tid = threadIdx.x;
  const int bid = blockIdx.x;

  if (bid < 268) {
    // ---------------- W3 pack ----------------
    const int idx  = bid * 256 + tid;            // 0..68607
    const int lane = idx & 63;
    int rest = idx >> 6;
    const int n  = rest & 1;  rest >>= 1;
    const int i2 = rest & 1;  rest >>= 1;        // rest = (os*67+ks) in [0,268)
    const int ks = rest % 67;
    const int os = rest / 67;

    const int o     = os * 32 + n * 16 + (lane & 15);
    const int slice = ks * 2 + i2;
    const int h0    = (lane >> 4) * 8;

    float v[8];
    if (slice < 133) {
      const float* src;
      if      (slice < 128) src = wW3 + ((size_t)o * 128 + slice) * 32 + h0;
      else if (slice < 132) src = wb3 + (size_t)o * 128 + (slice - 128) * 32 + h0;
      else                  src = bW3 + (size_t)o * 32 + h0;
      float4 a = *(const float4*)src;
      float4 b = *(const float4*)(src + 4);
      v[0]=a.x; v[1]=a.y; v[2]=a.z; v[3]=a.w; v[4]=b.x; v[5]=b.y; v[6]=b.z; v[7]=b.w;
    } else {
#pragma unroll
      for (int j = 0; j < 8; ++j) v[j] = 0.f;
    }
    h8v pk;
#pragma unroll
    for (int j = 0; j < 8; ++j) pk[j] = (f16)v[j];
    *(h8v*)(w3p + ((size_t)rest * 2048 + i2 * 1024 + n * 512 + lane * 8)) = pk;
    return;
  }

  // ---------------- hyper MLP + x cast ----------------
  const int hb = bid - 268;                      // 0..127

  {
    const size_t base = (size_t)hb * 16384;
#pragma unroll
    for (int u = 0; u < 16; ++u) {
      const size_t off = base + u * 1024 + tid * 4;
      float4 a = *(const float4*)(x + off);
      h4v p; p[0] = (f16)a.x; p[1] = (f16)a.y; p[2] = (f16)a.z; p[3] = (f16)a.w;
      *(h4v*)(xf + off) = p;
    }
  }

  const int br  = hb >> 6;                       // 0 = weight, 1 = bias branch
  const int tok = (hb & 63) * 256 + tid;
  const float* W1  = br ? bW1  : wW1;  const float* b1  = br ? bb1  : wb1;
  const float* g1  = br ? bg1  : wg1;  const float* be1 = br ? bbe1 : wbe1;
  const float* W2  = br ? bW2  : wW2;  const float* b2  = br ? bb2  : wb2;
  const float* g2  = br ? bg2  : wg2;  const float* be2 = br ? bbe2 : wbe2;
  f16* dst = (br ? h2b : h2w) + (size_t)tok * 32;

  const float z0 = z[tok * 3 + 0], z1 = z[tok * 3 + 1], z2 = z[tok * 3 + 2];

  float h1[32];
  float s = 0.f, s2 = 0.f;
#pragma unroll
  for (int j = 0; j < 32; ++j) {
    float v = W1[j * 3] * z0 + W1[j * 3 + 1] * z1 + W1[j * 3 + 2] * z2 + b1[j];
    h1[j] = v; s += v; s2 += v * v;
  }
  float mu  = s * (1.f / 32.f);
  float var = fmaxf(s2 * (1.f / 32.f) - mu * mu, 0.f);
  float rr  = rsqrtf(var + LN_EPS);
#pragma unroll
  for (int j = 0; j < 32; ++j)
    h1[j] = fmaxf((h1[j] - mu) * rr * g1[j] + be1[j], 0.f);

  float h2a[32];
  s = 0.f; s2 = 0.f;
#pragma unroll
  for (int j = 0; j < 32; ++j) {
    float acc = b2[j];
#pragma unroll
    for (int kk = 0; kk < 8; ++kk) {
      float4 w = *(const float4*)&W2[j * 32 + kk * 4];
      acc += w.x * h1[kk * 4] + w.y * h1[kk * 4 + 1]
           + w.z * h1[kk * 4 + 2] + w.w * h1[kk * 4 + 3];
    }
    h2a[j] = acc; s += acc; s2 += acc * acc;
  }
  mu  = s * (1.f / 32.f);
  var = fmaxf(s2 * (1.f / 32.f) - mu * mu, 0.f);
  rr  = rsqrtf(var + LN_EPS);
#pragma unroll
  for (int j8 = 0; j8 < 4; ++j8) {
    h8v pk;
#pragma unroll
    for (int j = 0; j < 8; ++j)
      pk[j] = (f16)fmaxf((h2a[j8*8+j] - mu) * rr * g2[j8*8+j] + be2[j8*8+j], 0.f);
    *(h8v*)(dst + j8 * 8) = pk;
  }
}

// ============================================================
// Kernel 2: U-GEMM, contiguous-B, internal splitK-4 via LDS reduce.
// grid 256 token-tiles, 1024 thr = 16 waves = 4 o-strips x 4 K-quarters.
// 1 block/CU, 4 waves/SIMD. Wave tile 64tok x 32o, 16 MFMA/iter,
// depth-2 reg double-buffer, barrier-free main loop.
// Quarters 1-3 dump acc to LDS; quarter 0 sums, adds bb3, stores.
// ============================================================
__global__ __launch_bounds__(1024, 4) void gemm_kernel(
    const f16* __restrict__ xf, const f16* __restrict__ w3p,
    const f16* __restrict__ h2w, const f16* __restrict__ h2b,
    const float* __restrict__ bb3, float* __restrict__ out)
{
  __shared__ __align__(16) f16 xs[64][136];     // x tile f16 (17.4 KB)
  __shared__ __align__(16) f32x4 red[3][4][8][64];  // partials (96 KB)

  const int tid   = threadIdx.x;
  const int lane  = tid & 63;
  const int wid   = tid >> 6;
  const int strip = wid & 3;
  const int q     = wid >> 2;                   // K-quarter
  const int lm    = lane & 15, hc = lane >> 4, hbase = hc * 8;
  const int t0    = blockIdx.x * 64;
  const int o0    = strip * 32;
  const int ks0   = q * 17;
  const int n_it  = (q == 3) ? 16 : 17;

  // ---- stage x tile (f16 global -> LDS), 16B per thread ----
  {
    const int r = tid >> 4, c = (tid & 15) * 8;
    *(h8v*)&xs[r][c] = *(const h8v*)(xf + (size_t)(t0 + r) * 128 + c);
  }

  // ---- per-lane h2 fragments ----
  uint32_t h2p[4][4];
#pragma unroll
  for (int m = 0; m < 4; ++m) {
    H8U c; c.v = *(const h8v*)(h2w + (size_t)(t0 + m * 16 + lm) * 32 + hbase);
#pragma unroll
    for (int qq = 0; qq < 4; ++qq) h2p[m][qq] = c.u[qq];
  }

  float bbv[2];
#pragma unroll
  for (int n = 0; n < 2; ++n)
    bbv[n] = (q == 0) ? bb3[o0 + n * 16 + lm] : 0.f;

  __syncthreads();   // xs ready

  // ---- contiguous B pointer: 4KB per iter, one 1KB wave-burst per frag ----
  const f16* bp = w3p + (size_t)(strip * 67 + ks0) * 2048 + lane * 8;

#define LOADSET(S) do { \
    S[0][0] = *(const h8v*)(bp); \
    S[0][1] = *(const h8v*)(bp + 512); \
    S[1][0] = *(const h8v*)(bp + 1024); \
    S[1][1] = *(const h8v*)(bp + 1536); \
    bp += 2048; } while (0)

  f32x4 acc[4][2];
#pragma unroll
  for (int m = 0; m < 4; ++m)
#pragma unroll
    for (int n = 0; n < 2; ++n) acc[m][n] = (f32x4){0.f, 0.f, 0.f, 0.f};

  auto STEP = [&](h8v (&bs)[2][2], int ks) {
    const int ksg = ks0 + ks;
    h8v af0[4], af1[4];
    if (__builtin_expect(ksg < 64, 1)) {
      // main slices: A = x * h2 (packed f16 muls)
#pragma unroll
      for (int m = 0; m < 4; ++m) {
        const uint32_t xp = *(const uint32_t*)&xs[m * 16 + lm][2 * ksg];
        H2U x0, x1;
        x0.u = (xp & 0xffffu) | (xp << 16);
        x1.u = (xp >> 16) | (xp & 0xffff0000u);
        H8U r0, r1;
#pragma unroll
        for (int qq = 0; qq < 4; ++qq) {
          H2U hq; hq.u = h2p[m][qq];
          H2U p0; p0.h = x0.h * hq.h; r0.u[qq] = p0.u;
          H2U p1; p1.h = x1.h * hq.h; r1.u[qq] = p1.u;
        }
        af0[m] = r0.v; af1[m] = r1.v;
      }
    } else if (ksg < 66) {
      // ext slices (b3 term): A = x directly
      const int s = (ksg - 64) * 2;
#pragma unroll
      for (int m = 0; m < 4; ++m) {
        af0[m] = *(const h8v*)&xs[m * 16 + lm][s * 32 + hbase];
        af1[m] = *(const h8v*)&xs[m * 16 + lm][(s + 1) * 32 + hbase];
      }
    } else {
      // bias slice (A = h2b); i2=1 pairs with zero B
#pragma unroll
      for (int m = 0; m < 4; ++m) {
        af0[m] = *(const h8v*)(h2b + (size_t)(t0 + m * 16 + lm) * 32 + hbase);
        af1[m] = af0[m];
      }
    }
#pragma unroll
    for (int n = 0; n < 2; ++n)
#pragma unroll
      for (int m = 0; m < 4; ++m)
        acc[m][n] = __builtin_amdgcn_mfma_f32_16x16x32_f16(af0[m], bs[0][n], acc[m][n], 0, 0, 0);
#pragma unroll
    for (int n = 0; n < 2; ++n)
#pragma unroll
      for (int m = 0; m < 4; ++m)
        acc[m][n] = __builtin_amdgcn_mfma_f32_16x16x32_f16(af1[m], bs[1][n], acc[m][n], 0, 0, 0);
  };

  h8v bA[2][2], bB[2][2];
  LOADSET(bA);            // ks = 0
  LOADSET(bB);            // ks = 1

  int ks = 0;
#pragma unroll 1
  while (ks + 2 <= n_it) {
    STEP(bA, ks);
    if (ks + 2 < n_it) LOADSET(bA);
    STEP(bB, ks + 1);
    if (ks + 3 < n_it) LOADSET(bB);
    ks += 2;
  }
  if (ks < n_it) STEP(bA, ks);
#undef LOADSET

  // ---- cross-quarter reduction through LDS ----
  if (q > 0) {
#pragma unroll
    for (int m = 0; m < 4; ++m)
#pragma unroll
      for (int n = 0; n < 2; ++n)
        red[q - 1][strip][m * 2 + n][lane] = acc[m][n];
  }
  __syncthreads();

  if (q == 0) {
#pragma unroll
    for (int m = 0; m < 4; ++m) {
#pragma unroll
      for (int n = 0; n < 2; ++n) {
        f32x4 r0 = red[0][strip][m * 2 + n][lane];
        f32x4 r1 = red[1][strip][m * 2 + n][lane];
        f32x4 r2 = red[2][strip][m * 2 + n][lane];
        f32x4 t  = acc[m][n] + r0 + r1 + r2;
        const int gc = o0 + n * 16 + lm;
#pragma unroll
        for (int r_ = 0; r_ < 4; ++r_) {
          const int row = t0 + m * 16 + hc * 4 + r_;
          out[(size_t)row * 128 + gc] = t[r_] + bbv[n];
        }
      }
    }
  }
}

// ============================================================
extern "C" void kernel_launch(void* const* d_in, const int* in_sizes, int n_in,
                              void* d_out, int out_size, void* d_ws, size_t ws_size,
                              hipStream_t stream)
{
  const float* x    = (const float*)d_in[0];
  const float* z    = (const float*)d_in[1];
  const float* wW1  = (const float*)d_in[2];
  const float* wb1  = (const float*)d_in[3];
  const float* wg1  = (const float*)d_in[4];
  const float* wbe1 = (const float*)d_in[5];
  const float* wW2  = (const float*)d_in[6];
  const float* wb2  = (const float*)d_in[7];
  const float* wg2  = (const float*)d_in[8];
  const float* wbe2 = (const float*)d_in[9];
  const float* wW3  = (const float*)d_in[10];
  const float* wb3  = (const float*)d_in[11];
  const float* bW1  = (const float*)d_in[12];
  const float* bb1  = (const float*)d_in[13];
  const float* bg1  = (const float*)d_in[14];
  const float* bbe1 = (const float*)d_in[15];
  const float* bW2  = (const float*)d_in[16];
  const float* bb2  = (const float*)d_in[17];
  const float* bg2  = (const float*)d_in[18];
  const float* bbe2 = (const float*)d_in[19];
  const float* bW3  = (const float*)d_in[20];
  const float* bb3  = (const float*)d_in[21];

  uint8_t* ws = (uint8_t*)d_ws;
  f16* w3p = (f16*)ws;                         // 1,097,728 B
  f16* xf  = (f16*)(ws + 1097728);             // 4,194,304 B
  f16* h2w = (f16*)(ws + 1097728 + 4194304);   // 1,048,576 B
  f16* h2b = (f16*)(ws + 1097728 + 4194304 + 1048576);
  float* outf = (float*)d_out;

  hipLaunchKernelGGL(prep_hyper, dim3(396), dim3(256), 0, stream,
                     x, z,
                     wW1, wb1, wg1, wbe1, wW2, wb2, wg2, wbe2,
                     bW1, bb1, bg1, bbe1, bW2, bb2, bg2, bbe2,
                     wW3, wb3, bW3,
                     w3p, xf, h2w, h2b);
  hipLaunchKernelGGL(gemm_kernel, dim3(256), dim3(1024), 0, stream,
                     xf, w3p, h2w, h2b, bb3, outf);
}